// Round 1
// baseline (491.664 us; speedup 1.0000x reference)
//
#include <hip/hip_runtime.h>
#include <hip/hip_bf16.h>
#include <cstdint>

typedef __bf16 bf16x8 __attribute__((ext_vector_type(8)));
typedef float f32x4 __attribute__((ext_vector_type(4)));

__device__ __forceinline__ unsigned short f2bf(float f) {
  union { float f; unsigned int u; } v; v.f = f;
  unsigned int r = v.u + 0x7fffu + ((v.u >> 16) & 1u);
  return (unsigned short)(r >> 16);
}

// ---------------- convert x: fp32 -> bf16 ----------------
__global__ void cvt_x_kernel(const float* __restrict__ x,
                             unsigned short* __restrict__ xb, int n4) {
  int i = blockIdx.x * blockDim.x + threadIdx.x;
  if (i >= n4) return;
  float4 v = ((const float4*)x)[i];
  ushort4 o;
  o.x = f2bf(v.x); o.y = f2bf(v.y); o.z = f2bf(v.z); o.w = f2bf(v.w);
  ((ushort4*)xb)[i] = o;
}

// ------- transpose+convert weights: w[K][N] fp32 -> wt[N][K] bf16 -------
__global__ void cvt_wt_kernel(const float* __restrict__ w,
                              unsigned short* __restrict__ wt, int K, int N) {
  __shared__ float tile[32][33];
  int nb = blockIdx.x * 32, kb = blockIdx.y * 32;
  int tx = threadIdx.x & 31, ty = threadIdx.x >> 5;
#pragma unroll
  for (int i = 0; i < 32; i += 8)
    tile[ty + i][tx] = w[(size_t)(kb + ty + i) * N + nb + tx];
  __syncthreads();
#pragma unroll
  for (int i = 0; i < 32; i += 8)
    wt[(size_t)(nb + ty + i) * K + kb + tx] = f2bf(tile[tx][ty + i]);
}

// ---------------- 128x128 bf16 GEMM, C = A[M,K] @ Bt[N,K]^T ----------------
// EPI 0: store bf16, EPI 1: store fp32
template <int EPI>
__global__ __launch_bounds__(256, 2)
void gemm128_kernel(const unsigned short* __restrict__ A,
                    const unsigned short* __restrict__ Bt,
                    void* __restrict__ C, int M, int N, int K) {
  __shared__ unsigned short As[128 * 72];  // 128 rows x 64 k, pitch 72
  __shared__ unsigned short Bs[128 * 72];  // 128 n-rows x 64 k, pitch 72
  const int tid = threadIdx.x;
  const int lane = tid & 63, wid = tid >> 6;
  const int m16 = lane & 15, quad = lane >> 4;
  const int rowBase = blockIdx.y * 128, colBase = blockIdx.x * 128;
  const int wm = (wid >> 1) * 64, wn = (wid & 1) * 64;

  f32x4 acc[4][4] = {};

  for (int k0 = 0; k0 < K; k0 += 64) {
    bf16x8 ra[4], rb[4];
#pragma unroll
    for (int it = 0; it < 4; it++) {
      int i = tid + it * 256;
      int r = i >> 3, kc = (i & 7) * 8;
      ra[it] = *(const bf16x8*)(A + (size_t)(rowBase + r) * K + k0 + kc);
      rb[it] = *(const bf16x8*)(Bt + (size_t)(colBase + r) * K + k0 + kc);
    }
#pragma unroll
    for (int it = 0; it < 4; it++) {
      int i = tid + it * 256;
      int r = i >> 3, kc = (i & 7) * 8;
      *(bf16x8*)(As + r * 72 + kc) = ra[it];
      *(bf16x8*)(Bs + r * 72 + kc) = rb[it];
    }
    __syncthreads();

    bf16x8 af[4][2], bfr[4][2];
#pragma unroll
    for (int rt = 0; rt < 4; rt++) {
      const unsigned short* p = As + (wm + rt * 16 + m16) * 72 + quad * 8;
      af[rt][0] = *(const bf16x8*)(p);
      af[rt][1] = *(const bf16x8*)(p + 32);
    }
#pragma unroll
    for (int ct = 0; ct < 4; ct++) {
      const unsigned short* p = Bs + (wn + ct * 16 + m16) * 72 + quad * 8;
      bfr[ct][0] = *(const bf16x8*)(p);
      bfr[ct][1] = *(const bf16x8*)(p + 32);
    }
#pragma unroll
    for (int rt = 0; rt < 4; rt++)
#pragma unroll
      for (int ct = 0; ct < 4; ct++) {
        acc[rt][ct] = __builtin_amdgcn_mfma_f32_16x16x32_bf16(
            af[rt][0], bfr[ct][0], acc[rt][ct], 0, 0, 0);
        acc[rt][ct] = __builtin_amdgcn_mfma_f32_16x16x32_bf16(
            af[rt][1], bfr[ct][1], acc[rt][ct], 0, 0, 0);
      }
    __syncthreads();
  }

#pragma unroll
  for (int rt = 0; rt < 4; rt++)
#pragma unroll
    for (int ct = 0; ct < 4; ct++)
#pragma unroll
      for (int r = 0; r < 4; r++) {
        int grow = rowBase + wm + rt * 16 + quad * 4 + r;
        int gcol = colBase + wn + ct * 16 + m16;
        float v = acc[rt][ct][r];
        if (EPI == 0)
          ((unsigned short*)C)[(size_t)grow * N + gcol] = f2bf(v);
        else
          ((float*)C)[(size_t)grow * N + gcol] = v;
      }
}

// ---------------- flash attention ----------------
// qkv: bf16 [4][2048][3072] (q|k|v each 1024 cols, head h at h*64)
// yb : bf16 [4][2048][1024]  ([b][t][h*64+d])
__global__ __launch_bounds__(256, 4)
void attn_kernel(const unsigned short* __restrict__ qkv,
                 unsigned short* __restrict__ yb) {
  __shared__ unsigned short Ks[64 * 72];       // [key][d] pitch 72
  __shared__ unsigned short Vt[64 * 72];       // [d][key] pitch 72
  __shared__ unsigned short Ps[4 * 16 * 72];   // per-wave P [qrow][key]

  const int tid = threadIdx.x;
  const int lane = tid & 63, wave = tid >> 6;
  const int m16 = lane & 15, quad = lane >> 4;
  const int bb = blockIdx.y >> 4, hh = blockIdx.y & 15;
  const int qt = (gridDim.x - 1) - blockIdx.x;  // big tiles first
  const int q0 = qt * 64;
  const int qrow_base = q0 + wave * 16;

  const size_t batch_off = (size_t)bb * 2048 * 3072;

  // Q fragments (A-layout), stay in registers for the whole kernel
  const unsigned short* qb =
      qkv + batch_off + (size_t)(qrow_base + m16) * 3072 + hh * 64;
  const bf16x8 aQ0 = *(const bf16x8*)(qb + quad * 8);
  const bf16x8 aQ1 = *(const bf16x8*)(qb + 32 + quad * 8);

  float mi[4], li[4];
  f32x4 o[4] = {};
#pragma unroll
  for (int r = 0; r < 4; r++) { mi[r] = -1e30f; li[r] = 0.f; }

  const int ntiles = qt + 1;
  for (int kt = 0; kt < ntiles; kt++) {
    const int k0 = kt * 64;
    // ---- stage K and V^T ----
    {
      bf16x8 kv[2], vv[2];
#pragma unroll
      for (int it = 0; it < 2; it++) {
        int i = tid + it * 256;
        int key = i >> 3, dc = (i & 7) * 8;
        const unsigned short* src =
            qkv + batch_off + (size_t)(k0 + key) * 3072 + hh * 64;
        kv[it] = *(const bf16x8*)(src + 1024 + dc);
        vv[it] = *(const bf16x8*)(src + 2048 + dc);
      }
#pragma unroll
      for (int it = 0; it < 2; it++) {
        int i = tid + it * 256;
        int key = i >> 3, dc = (i & 7) * 8;
        *(bf16x8*)(Ks + key * 72 + dc) = kv[it];
        const unsigned short* vp = (const unsigned short*)&vv[it];
#pragma unroll
        for (int j = 0; j < 8; j++) Vt[(dc + j) * 72 + key] = vp[j];
      }
    }
    __syncthreads();

    // ---- S = Q K^T (C-layout) ----
    f32x4 s[4];
#pragma unroll
    for (int ct = 0; ct < 4; ct++) {
      const unsigned short* p = Ks + (ct * 16 + m16) * 72 + quad * 8;
      bf16x8 bk0 = *(const bf16x8*)(p);
      bf16x8 bk1 = *(const bf16x8*)(p + 32);
      f32x4 a = {0.f, 0.f, 0.f, 0.f};
      a = __builtin_amdgcn_mfma_f32_16x16x32_bf16(aQ0, bk0, a, 0, 0, 0);
      a = __builtin_amdgcn_mfma_f32_16x16x32_bf16(aQ1, bk1, a, 0, 0, 0);
      s[ct] = a;
    }

    // ---- scale + causal mask ----
#pragma unroll
    for (int ct = 0; ct < 4; ct++) {
      int key = k0 + ct * 16 + m16;
#pragma unroll
      for (int r = 0; r < 4; r++) {
        int qr = qrow_base + quad * 4 + r;
        float v = s[ct][r] * 0.125f;
        s[ct][r] = (key > qr) ? -1e30f : v;
      }
    }

    // ---- online softmax (row stats across the 16-lane group) ----
    float cand[4], rs[4], al[4];
#pragma unroll
    for (int r = 0; r < 4; r++)
      cand[r] = fmaxf(fmaxf(s[0][r], s[1][r]), fmaxf(s[2][r], s[3][r]));
#pragma unroll
    for (int off = 1; off < 16; off <<= 1)
#pragma unroll
      for (int r = 0; r < 4; r++)
        cand[r] = fmaxf(cand[r], __shfl_xor(cand[r], off));
#pragma unroll
    for (int r = 0; r < 4; r++) {
      float mnew = fmaxf(mi[r], cand[r]);
      al[r] = __expf(mi[r] - mnew);
      mi[r] = mnew;
    }
#pragma unroll
    for (int ct = 0; ct < 4; ct++)
#pragma unroll
      for (int r = 0; r < 4; r++)
        s[ct][r] = __expf(s[ct][r] - mi[r]);
#pragma unroll
    for (int r = 0; r < 4; r++)
      rs[r] = s[0][r] + s[1][r] + s[2][r] + s[3][r];
#pragma unroll
    for (int off = 1; off < 16; off <<= 1)
#pragma unroll
      for (int r = 0; r < 4; r++) rs[r] += __shfl_xor(rs[r], off);
#pragma unroll
    for (int r = 0; r < 4; r++) li[r] = li[r] * al[r] + rs[r];
#pragma unroll
    for (int dt = 0; dt < 4; dt++)
#pragma unroll
      for (int r = 0; r < 4; r++) o[dt][r] *= al[r];

    // ---- P: C-layout -> LDS -> A-layout ----
    unsigned short* pw = Ps + wave * (16 * 72);
#pragma unroll
    for (int ct = 0; ct < 4; ct++)
#pragma unroll
      for (int r = 0; r < 4; r++)
        pw[(quad * 4 + r) * 72 + ct * 16 + m16] = f2bf(s[ct][r]);
    asm volatile("s_waitcnt lgkmcnt(0)" ::: "memory");
    const bf16x8 aP0 = *(const bf16x8*)(pw + m16 * 72 + quad * 8);
    const bf16x8 aP1 = *(const bf16x8*)(pw + m16 * 72 + 32 + quad * 8);

    // ---- O += P V ----
#pragma unroll
    for (int dt = 0; dt < 4; dt++) {
      const unsigned short* p = Vt + (dt * 16 + m16) * 72 + quad * 8;
      bf16x8 bv0 = *(const bf16x8*)(p);
      bf16x8 bv1 = *(const bf16x8*)(p + 32);
      o[dt] = __builtin_amdgcn_mfma_f32_16x16x32_bf16(aP0, bv0, o[dt], 0, 0, 0);
      o[dt] = __builtin_amdgcn_mfma_f32_16x16x32_bf16(aP1, bv1, o[dt], 0, 0, 0);
    }
    __syncthreads();
  }

  // ---- epilogue: O /= l, store bf16 ----
#pragma unroll
  for (int dt = 0; dt < 4; dt++)
#pragma unroll
    for (int r = 0; r < 4; r++) {
      int row = qrow_base + quad * 4 + r;
      float v = o[dt][r] / li[r];
      yb[((size_t)bb * 2048 + row) * 1024 + hh * 64 + dt * 16 + m16] = f2bf(v);
    }
}

// ---------------- launch ----------------
extern "C" void kernel_launch(void* const* d_in, const int* in_sizes, int n_in,
                              void* d_out, int out_size, void* d_ws,
                              size_t ws_size, hipStream_t stream) {
  const float* x = (const float*)d_in[0];       // [4,2048,1024]
  const float* wqkv = (const float*)d_in[1];    // [1024,3072]
  const float* wproj = (const float*)d_in[2];   // [1024,1024]
  float* out = (float*)d_out;                   // [4,2048,1024] fp32

  unsigned short* Xb = (unsigned short*)d_ws;            // 8192*1024
  unsigned short* Wqkv_t = Xb + (size_t)8192 * 1024;     // 3072*1024
  unsigned short* Wp_t = Wqkv_t + (size_t)3072 * 1024;   // 1024*1024
  unsigned short* QKV = Wp_t + (size_t)1024 * 1024;      // 8192*3072
  unsigned short* Yb = QKV + (size_t)8192 * 3072;        // 8192*1024

  cvt_x_kernel<<<dim3(8192), dim3(256), 0, stream>>>(x, Xb, 2097152);
  cvt_wt_kernel<<<dim3(96, 32), dim3(256), 0, stream>>>(wqkv, Wqkv_t, 1024, 3072);
  cvt_wt_kernel<<<dim3(32, 32), dim3(256), 0, stream>>>(wproj, Wp_t, 1024, 1024);

  gemm128_kernel<0><<<dim3(24, 64), dim3(256), 0, stream>>>(
      Xb, Wqkv_t, (void*)QKV, 8192, 3072, 1024);

  attn_kernel<<<dim3(32, 64), dim3(256), 0, stream>>>(QKV, Yb);

  gemm128_kernel<1><<<dim3(8, 64), dim3(256), 0, stream>>>(
      Yb, Wp_t, (void*)out, 8192, 1024, 1024);
}